// Round 17
// baseline (91.773 us; speedup 1.0000x reference)
//
#include <hip/hip_runtime.h>
#include <hip/hip_bf16.h>
#include <math.h>

#define B_ 32
#define L_ 1024
#define D_ 256

typedef _Float16 half8 __attribute__((ext_vector_type(8)));
typedef __fp16   fp16x2 __attribute__((ext_vector_type(2)));
typedef short    s16x8 __attribute__((ext_vector_type(8)));
typedef float    f32x4 __attribute__((ext_vector_type(4)));

typedef __attribute__((address_space(3))) unsigned int lds_u32;
typedef __attribute__((address_space(1))) unsigned int gbl_u32;

__device__ __forceinline__ void gl_lds16(const void* g, void* l) {
    __builtin_amdgcn_global_load_lds((gbl_u32*)g, (lds_u32*)l, 16, 0, 0);
}

__device__ __forceinline__ unsigned short f2bf(float x) {
    unsigned u = __float_as_uint(x);
    u += 0x7FFFu + ((u >> 16) & 1u);
    return (unsigned short)(u >> 16);
}

__device__ __forceinline__ unsigned short f2h(float x) {
    _Float16 h = (_Float16)x;
    unsigned short u;
    __builtin_memcpy(&u, &h, 2);
    return u;
}

__device__ __forceinline__ unsigned pkrtz(float a, float b) {
    fp16x2 v = __builtin_amdgcn_cvt_pkrtz(a, b);
    unsigned u;
    __builtin_memcpy(&u, &v, 4);
    return u;
}

// counted waitcnt + raw barrier (avoid __syncthreads' vmcnt(0) drain)
#define WAITVL(N) asm volatile("s_waitcnt vmcnt(" #N ") lgkmcnt(0)" ::: "memory")
#define WAITV(N)  asm volatile("s_waitcnt vmcnt(" #N ")" ::: "memory")
#define BARRIER()  do { __builtin_amdgcn_s_barrier(); __builtin_amdgcn_sched_barrier(0); } while (0)

// ---------------------------------------------------------------------------
// W-prep: Wt[z][n][k] = fp16(W[z][k][n]) via LDS 64x64 tile transpose.
// ---------------------------------------------------------------------------
__global__ __launch_bounds__(256) void wprep_kernel(
    const float* __restrict__ W0, const float* __restrict__ W1,
    const float* __restrict__ W2, unsigned short* __restrict__ Wt)
{
    const int z = blockIdx.z;
    const float* __restrict__ W = (z == 0) ? W0 : (z == 1) ? W1 : W2;
    __shared__ unsigned short T[64][72];
    const int k0 = blockIdx.x << 6, n0 = blockIdx.y << 6;
    const int t = threadIdx.x;
    const int r = t >> 2, c0 = (t & 3) << 4;
    #pragma unroll
    for (int j = 0; j < 16; j += 4) {
        float4 w4 = *(const float4*)(W + (size_t)(k0 + r) * 256 + n0 + c0 + j);
        T[c0 + j + 0][r] = f2h(w4.x);
        T[c0 + j + 1][r] = f2h(w4.y);
        T[c0 + j + 2][r] = f2h(w4.z);
        T[c0 + j + 3][r] = f2h(w4.w);
    }
    __syncthreads();
    const int n = t >> 2, kc = (t & 3) << 4;
    unsigned short* dst = Wt + ((size_t)z << 16) + (size_t)(n0 + n) * 256 + k0 + kc;
    *(uint4*)(dst + 0) = *(const uint4*)&T[n][kc + 0];
    *(uint4*)(dst + 8) = *(const uint4*)&T[n][kc + 8];
}

// ---------------------------------------------------------------------------
// Projection GEMM, fp16 MFMA 16x16x32. C[M=32768,256] = A @ W.
// BM=128, BN=256 (A read once), BK=64, 1024 threads (16 waves 4Mx4N).
// ALL staging via gl_lds (A kept fp32 in LDS; fragments = 2x ds_read_b128 +
// 4x pkrtz). Counted-vmcnt schedule (T3/T4): prefetch never drained:
//   [stage(next) 4 loads | vmcnt(4)+barrier | compute(buf) | barrier]
// LDS 128 KB: A-f32 dbuf 2x32K + B-f16 dbuf 2x32K. 16B-chunk XOR swizzles.
// z<2: Cs[128][264] coalesced epilogue. z=2: two-pass Tt transpose -> Vt.
// ---------------------------------------------------------------------------
__global__ __launch_bounds__(1024, 4) void proj_mfma_kernel(
    const float* __restrict__ A0, const float* __restrict__ A1,
    const float* __restrict__ A2, const unsigned short* __restrict__ Wt,
    unsigned short* __restrict__ Qh, unsigned short* __restrict__ Kh,
    unsigned short* __restrict__ Vt)
{
    __shared__ __align__(16) unsigned char SMEMRAW[131072];   // 128 KB
    float*          Asm = (float*)SMEMRAW;                    // [buf][128*64] f32
    unsigned short* Bsm = (unsigned short*)(SMEMRAW + 65536); // [buf][256*64] f16

    const int fblk = blockIdx.x;
    const int xt = fblk & 255;               // M-tile 0..255
    const int z  = fblk >> 8;                // 0..2
    const int bm = xt << 7;

    const float* __restrict__ A = (z == 0) ? A0 : (z == 1) ? A1 : A2;
    const int t = threadIdx.x, lane = t & 63, w = t >> 6;
    const int wm = (w >> 2) << 5, wn = (w & 3) << 6;   // 4M x 4N, 32q x 64n

    const float* __restrict__ Ag = A + (size_t)bm * 256;
    const unsigned short* __restrict__ Bg = Wt + ((size_t)z << 16);

    f32x4 acc[2][4];
    const f32x4 z4 = {0.f, 0.f, 0.f, 0.f};
    #pragma unroll
    for (int mi = 0; mi < 2; ++mi)
        #pragma unroll
        for (int ni = 0; ni < 4; ++ni) acc[mi][ni] = z4;

    auto stageA = [&](int buf, int it) {
        #pragma unroll
        for (int i = 0; i < 2; ++i) {
            int o = (i << 10) + t;           // 0..2047 chunks of 16B (4 f32)
            int r = o >> 4, c = o & 15;      // 128 rows x 16 chunks
            int cs = (c & 8) | ((c & 7) ^ (r & 7));
            gl_lds16(Ag + (size_t)r * 256 + (it << 6) + (cs << 2),
                     &Asm[(buf << 13) + (o << 2)]);
        }
    };
    auto stageB = [&](int buf, int it) {
        #pragma unroll
        for (int i = 0; i < 2; ++i) {
            int o = (i << 10) + t;           // 0..2047 chunks of 8 halves
            int r = o >> 3, c = o & 7;       // 256 rows x 8 chunks
            int cs = c ^ (r & 7);
            gl_lds16(Bg + (size_t)r * 256 + (it << 6) + (cs << 3),
                     &Bsm[(buf << 14) + (o << 3)]);
        }
    };
    auto compute = [&](int buf) {
        #pragma unroll
        for (int kc = 0; kc < 2; ++kc) {
            half8 af[2], bfr[4];
            #pragma unroll
            for (int mi = 0; mi < 2; ++mi) {
                int m  = wm + (mi << 4) + (lane & 15);
                int g2 = (lane >> 4) << 1;
                int cs0 = (kc << 3) | ( g2      ^ (m & 7));
                int cs1 = (kc << 3) | ((g2 | 1) ^ (m & 7));
                float4 lo = *(const float4*)&Asm[(buf << 13) + (m << 6) + (cs0 << 2)];
                float4 hi = *(const float4*)&Asm[(buf << 13) + (m << 6) + (cs1 << 2)];
                unsigned hh[4];
                hh[0] = pkrtz(lo.x, lo.y); hh[1] = pkrtz(lo.z, lo.w);
                hh[2] = pkrtz(hi.x, hi.y); hh[3] = pkrtz(hi.z, hi.w);
                __builtin_memcpy(&af[mi], hh, 16);
            }
            #pragma unroll
            for (int ni = 0; ni < 4; ++ni) {
                int n = wn + (ni << 4) + (lane & 15);
                int cs = ((kc << 2) + (lane >> 4)) ^ (n & 7);
                bfr[ni] = *(const half8*)&Bsm[(buf << 14) + (n << 6) + (cs << 3)];
            }
            #pragma unroll
            for (int mi = 0; mi < 2; ++mi)
                #pragma unroll
                for (int ni = 0; ni < 4; ++ni)
                    acc[mi][ni] = __builtin_amdgcn_mfma_f32_16x16x32_f16(
                        af[mi], bfr[ni], acc[mi][ni], 0, 0, 0);
        }
    };

    // prologue: tile 0 staged, one-time full drain
    stageA(0, 0); stageB(0, 0);
    WAITVL(0); BARRIER();

    // it 0
    stageA(1, 1); stageB(1, 1);
    WAITVL(4); BARRIER();        // tile0 ready everywhere; tile1 in flight
    compute(0);
    BARRIER();                   // WAR: all waves done reading buf0
    // it 1
    stageA(0, 2); stageB(0, 2);
    WAITVL(4); BARRIER();        // tile1 ready; tile2 in flight
    compute(1);
    BARRIER();
    // it 2
    stageA(1, 3); stageB(1, 3);
    WAITVL(4); BARRIER();        // tile2 ready; tile3 in flight
    compute(0);
    BARRIER();
    // it 3
    WAITVL(0); BARRIER();        // tile3 ready
    compute(1);

    if (z < 2) {
        unsigned short* __restrict__ C = (z == 0) ? Qh : Kh;
        __syncthreads();   // all LDS reads done before overlay
        unsigned short (*Cs)[264] = (unsigned short(*)[264])SMEMRAW;  // 67.6 KB
        #pragma unroll
        for (int mi = 0; mi < 2; ++mi) {
            int q0l = wm + (mi << 4) + ((lane >> 4) << 2);
            #pragma unroll
            for (int ni = 0; ni < 4; ++ni) {
                int cl = wn + (ni << 4) + (lane & 15);
                #pragma unroll
                for (int r = 0; r < 4; ++r)
                    Cs[q0l + r][cl] = f2h(acc[mi][ni][r]);
            }
        }
        __syncthreads();
        #pragma unroll
        for (int i = 0; i < 4; ++i) {
            int o = (i << 10) + t;           // 0..4095 chunks of 8 halves
            int r = o >> 5, c = o & 31;      // 128 rows x 32 chunks
            *(uint4*)(C + (size_t)(bm + r) * 256 + (c << 3)) =
                *(const uint4*)&Cs[r][c << 3];
        }
    } else {
        // two-pass transpose: pass dh covers d in [dh*128, dh*128+128)
        unsigned short (*Tt)[136] = (unsigned short(*)[136])SMEMRAW;  // 34.8 KB
        const int bb = bm >> 10, kin = bm & 1023;
        #pragma unroll
        for (int dh = 0; dh < 2; ++dh) {
            __syncthreads();   // previous reads/stores done before overwrite
            if (((w & 3) >> 1) == dh) {
                #pragma unroll
                for (int mi = 0; mi < 2; ++mi) {
                    int m0 = wm + (mi << 4) + ((lane >> 4) << 2);
                    #pragma unroll
                    for (int ni = 0; ni < 4; ++ni) {
                        int nl = (wn & 127) + (ni << 4) + (lane & 15);
                        #pragma unroll
                        for (int r = 0; r < 4; ++r)
                            Tt[nl][m0 + r] = f2bf(acc[mi][ni][r]);
                    }
                }
            }
            __syncthreads();
            int dr = t >> 3, cq = t & 7;
            unsigned short* dst = Vt + ((size_t)bb * 256 + (dh << 7) + dr) * 1024
                                  + kin + (cq << 4);
            *(uint4*)(dst + 0) = *(const uint4*)&Tt[dr][(cq << 4) + 0];
            *(uint4*)(dst + 8) = *(const uint4*)&Tt[dr][(cq << 4) + 8];
        }
    }
}

// ---------------------------------------------------------------------------
// Fused flash attention, QBLK=128, KB=64, 256 blocks (1/CU), 1024 threads.
// Double-buffered K [2][64][256] + V [2][256][64] + XOR-swizzled Ps [128][64]
// = 144 KB LDS. Counted-vmcnt schedule (prefetch stays in flight across
// barriers): stageK+stageV(kt+1) at loop top; barrier B = vmcnt(4)+lgkmcnt(0)
// (V(kt) oldest -> done; P visible); barrier A = vmcnt(2) (K(kt+1) done,
// V(kt+1) still in flight). Tail uses vmcnt(0).
// S waves 8(M)x2(N): 16q x 32k, Q in regs. PV waves 4(M)x4(N): 32q x 64d.
// XCD decode: 8 q-tiles of a batch share f%8 -> 4 batches/XCD L2-resident.
// ---------------------------------------------------------------------------
__global__ __launch_bounds__(1024, 4) void fused_attn_kernel(
    const unsigned short* __restrict__ Qh, const unsigned short* __restrict__ Kh,
    const unsigned short* __restrict__ Vt, const int* __restrict__ mask,
    float* __restrict__ Out)
{
    __shared__ unsigned short Ks[2][16384];  // [64][256] halves x2, 64 KB
    __shared__ unsigned short Vs[2][16384];  // [256][64] halves x2, 64 KB
    __shared__ unsigned short Ps[128 * 64];  // 16 KB bf16, XOR-swizzled chunks
    float* lredp = (float*)Ps;               // overlay, used after the loop

    // XCD-aware decode: f = xcd + 8*qtile + 64*batchgroup
    const int f  = blockIdx.x;
    const int b  = (f & 7) + ((f >> 6) << 3);
    const int q0 = ((f >> 3) & 7) << 7;
    const size_t bL = (size_t)b * L_;
    const int t = threadIdx.x, lane = t & 63, w = t >> 6;
    const int wm_s = (w >> 1) << 4, wn_s = (w & 1) << 5;   // S: 8x2, 16q x 32k
    const int wm_v = (w >> 2) << 5, wn_v = (w & 3) << 6;   // PV: 4x4, 32q x 64d

    const unsigned short* __restrict__ Kb = Kh + (bL << 8);
    const unsigned short* __restrict__ Vb = Vt + (bL << 8);

    auto stageK = [&](int buf, int kt) {
        #pragma unroll
        for (int i = 0; i < 1; ++i) { }
        #pragma unroll
        for (int i = 0; i < 2; ++i) {
            int o = (i << 10) + t;           // 0..2047 chunks of 8 halves
            int r = o >> 5, c = o & 31;
            int cs = (c & 24) | ((c & 7) ^ (r & 7));
            gl_lds16(Kb + (size_t)((kt << 6) + r) * 256 + (cs << 3), &Ks[buf][o << 3]);
        }
    };
    auto stageV = [&](int buf, int kt) {
        #pragma unroll
        for (int i = 0; i < 2; ++i) {
            int o = (i << 10) + t;           // 0..2047
            int d = o >> 3, c = o & 7;
            int cs = c ^ (d & 7);
            gl_lds16(Vb + ((size_t)d << 10) + (kt << 6) + (cs << 3), &Vs[buf][o << 3]);
        }
    };

    // prologue: Q frags + mask first (their vmcnt drained once below)
    half8 qf[8];
    {
        int m = wm_s + (lane & 15);
        const unsigned short* qp = Qh + ((bL + q0 + m) << 8) + ((lane >> 4) << 3);
        #pragma unroll
        for (int kc = 0; kc < 8; ++kc)
            qf[kc] = *(const half8*)(qp + (kc << 5));
    }
    int mv[4];
    {
        int qrow = wm_s + ((lane >> 4) << 2);
        #pragma unroll
        for (int r = 0; r < 4; ++r) mv[r] = mask[bL + q0 + qrow + r];
    }
    stageK(0, 0);
    stageV(0, 0);

    f32x4 o_acc[2][4];
    const f32x4 z4 = {0.f, 0.f, 0.f, 0.f};
    #pragma unroll
    for (int mi = 0; mi < 2; ++mi)
        #pragma unroll
        for (int ni = 0; ni < 4; ++ni) o_acc[mi][ni] = z4;
    float lacc[4] = {};

    WAITVL(0); BARRIER();   // tile 0 staged everywhere (one-time drain)

    for (int kt = 0; kt < 16; ++kt) {
        const int cur = kt & 1;
        if (kt < 15) {                       // prefetch kt+1: K first (oldest)
            stageK(cur ^ 1, kt + 1);
            stageV(cur ^ 1, kt + 1);
        }

        // ---- S = Q . K^T (wave tile 16q x 32k), Q in regs ----
        f32x4 accs[2];
        accs[0] = z4; accs[1] = z4;
        #pragma unroll
        for (int kc = 0; kc < 8; ++kc) {
            int kb = (kc >> 1) << 6, cc = ((kc & 1) << 2) + (lane >> 4);
            int n0 = wn_s + (lane & 15);
            int n1 = n0 + 16;
            half8 bf0 = *(const half8*)&Ks[cur][(n0 << 8) + kb + ((cc ^ (n0 & 7)) << 3)];
            half8 bf1 = *(const half8*)&Ks[cur][(n1 << 8) + kb + ((cc ^ (n1 & 7)) << 3)];
            accs[0] = __builtin_amdgcn_mfma_f32_16x16x32_f16(qf[kc], bf0, accs[0], 0, 0, 0);
            accs[1] = __builtin_amdgcn_mfma_f32_16x16x32_f16(qf[kc], bf1, accs[1], 0, 0, 0);
        }

        // ---- P = exp(S) (mask -> 1), bf16 to swizzled LDS, accumulate l ----
        {
            int qrow = wm_s + ((lane >> 4) << 2);
            #pragma unroll
            for (int ni = 0; ni < 2; ++ni) {
                int kl = wn_s + (ni << 4) + (lane & 15);
                #pragma unroll
                for (int r = 0; r < 4; ++r) {
                    int q = qrow + r;
                    float p = mv[r] ? __expf(accs[ni][r]) : 1.0f;
                    Ps[(q << 6) + ((((kl >> 3) ^ (q & 7)) << 3)) + (kl & 7)] = f2bf(p);
                    lacc[r] += p;
                }
            }
        }
        // barrier B: P visible; V(kt) complete (oldest beyond the 4 new)
        if (kt < 15) { WAITVL(4); } else { WAITVL(0); }
        BARRIER();

        // ---- O += P . V (wave tile 32q x 64d) ----
        #pragma unroll
        for (int kc2 = 0; kc2 < 2; ++kc2) {
            s16x8 pa[2], vb[4];
            int cc = (kc2 << 2) + (lane >> 4);
            #pragma unroll
            for (int mi = 0; mi < 2; ++mi) {
                int m = wm_v + (mi << 4) + (lane & 15);
                pa[mi] = *(const s16x8*)&Ps[(m << 6) + ((cc ^ (m & 7)) << 3)];
            }
            #pragma unroll
            for (int ni = 0; ni < 4; ++ni) {
                int n = wn_v + (ni << 4) + (lane & 15);
                vb[ni] = *(const s16x8*)&Vs[cur][(n << 6) + ((cc ^ (n & 7)) << 3)];
            }
            #pragma unroll
            for (int mi = 0; mi < 2; ++mi)
                #pragma unroll
                for (int ni = 0; ni < 4; ++ni)
                    o_acc[mi][ni] = __builtin_amdgcn_mfma_f32_16x16x32_bf16(
                        pa[mi], vb[ni], o_acc[mi][ni], 0, 0, 0);
        }
        // barrier A: K(kt+1) complete (oldest 2); V(kt+1) stays in flight;
        // WAR: everyone done reading Ks/Vs[cur^1... wait: cur] + Ps
        if (kt < 15) { WAITV(2); }
        BARRIER();
    }

    // ---- l reduction (Ps memory reused as lred[128][2]) ----
    #pragma unroll
    for (int r = 0; r < 4; ++r) {
        float v = lacc[r];
        v += __shfl_xor(v, 1);
        v += __shfl_xor(v, 2);
        v += __shfl_xor(v, 4);
        v += __shfl_xor(v, 8);
        if ((lane & 15) == 0)
            lredp[((wm_s + ((lane >> 4) << 2) + r) << 1) + (w & 1)] = v;
    }
    __syncthreads();

    // ---- epilogue: Out = O / l ----
    #pragma unroll
    for (int mi = 0; mi < 2; ++mi) {
        #pragma unroll
        for (int rr = 0; rr < 4; ++rr) {
            int q = wm_v + (mi << 4) + ((lane >> 4) << 2) + rr;
            float inv = 1.0f / (lredp[q << 1] + lredp[(q << 1) + 1]);
            #pragma unroll
            for (int ni = 0; ni < 4; ++ni) {
                int d = wn_v + (ni << 4) + (lane & 15);
                Out[((bL + q0 + q) << 8) + d] = o_acc[mi][ni][rr] * inv;
            }
        }
    }
}

extern "C" void kernel_launch(void* const* d_in, const int* in_sizes, int n_in,
                              void* d_out, int out_size, void* d_ws, size_t ws_size,
                              hipStream_t stream) {
    const float* rq = (const float*)d_in[0];
    const float* rk = (const float*)d_in[1];
    const float* rv = (const float*)d_in[2];
    const int*   vm = (const int*)d_in[3];
    const float* WQ = (const float*)d_in[4];
    const float* WK = (const float*)d_in[5];
    const float* WV = (const float*)d_in[6];
    float* out = (float*)d_out;

    char* ws = (char*)d_ws;
    unsigned short* Qh = (unsigned short*)(ws);                          // 16 MB fp16 [b*L][D]
    unsigned short* Kh = (unsigned short*)(ws + ((size_t)16 << 20));     // 16 MB fp16 [b*L][D]
    unsigned short* Vt = (unsigned short*)(ws + ((size_t)32 << 20));     // 16 MB bf16 [b][D][LK]
    unsigned short* Wt = (unsigned short*)(ws + ((size_t)48 << 20));     // 384 KB fp16 [3][256][256]

    dim3 wg(4, 4, 3);
    wprep_kernel<<<wg, 256, 0, stream>>>(WQ, WK, WV, Wt);

    proj_mfma_kernel<<<768, 1024, 0, stream>>>(rq, rk, rv, Wt, Qh, Kh, Vt);

    fused_attn_kernel<<<256, 1024, 0, stream>>>(Qh, Kh, Vt, vm, out);
}